// Round 8
// baseline (870.126 us; speedup 1.0000x reference)
//
#include <hip/hip_runtime.h>
#include <hip/hip_bf16.h>

// ---------------------------------------------------------------------------
// Qwen3.5 GatedDeltaNet forward, MI355X (gfx950)
// B=2 S=2048 HIDDEN=2048 HK=16 HV=32 DK=DV=128 KCONV=4 CHUNK=64
// R9->R10: (1) scan_kernel prefetch deepened to 3 register sets (loads
// issued ~2 chunk-times ahead; 1 wave/SIMD so VGPR is free); (2) ba_kernel
// 4x TLP (grid 1024, 1 row/wave) + float4 H loads; (3) gemm256_bt XCD
// swizzle removed (data is L3-resident; swizzle costs ~2% in that regime
// per m160) — counter-verifiable A/B in top-5.
// GEMM2/conv/gate/chunk frozen at R7 state.
// Workspace: 370,155,520 B with region aliasing (see kernel_launch).
// ---------------------------------------------------------------------------

typedef short bf16x8 __attribute__((ext_vector_type(8)));
typedef float f32x4  __attribute__((ext_vector_type(4)));

#define MFMA_BF16(a,b,c) __builtin_amdgcn_mfma_f32_16x16x32_bf16((a),(b),(c),0,0,0)
#define GLD16(g,l) __builtin_amdgcn_global_load_lds((const __attribute__((address_space(1))) void*)(g), (__attribute__((address_space(3))) void*)(l), 16, 0, 0)

__device__ __forceinline__ unsigned short f2bf(float x){
  union { float f; unsigned u; } v; v.f = x;
  return (unsigned short)((v.u + 0x7fffu + ((v.u >> 16) & 1u)) >> 16);
}
__device__ __forceinline__ float bf2f(unsigned short h){
  union { unsigned u; float f; } v; v.u = ((unsigned)h) << 16; return v.f;
}
__device__ __forceinline__ unsigned long long pack4bf(float a, float b, float c, float d){
  return (unsigned long long)f2bf(a) | ((unsigned long long)f2bf(b) << 16)
       | ((unsigned long long)f2bf(c) << 32) | ((unsigned long long)f2bf(d) << 48);
}

// ---------------------------------------------------------------------------
__global__ __launch_bounds__(256) void cast_bf16_kernel(
    const float* __restrict__ in, unsigned short* __restrict__ out, int n)
{
  int i = (blockIdx.x * 256 + threadIdx.x) * 4;
  if (i >= n) return;
  float4 v = *(const float4*)(in + i);
  *(unsigned long long*)(out + i) = pack4bf(v.x, v.y, v.z, v.w);
}

// transpose + cast: W[R][C] f32 -> WT[C][R] bf16
__global__ __launch_bounds__(256) void transpose_cast_kernel(
    const float* __restrict__ W, unsigned short* __restrict__ WT, int R, int C)
{
  __shared__ __attribute__((aligned(16))) float tile[32][33];
  int c0 = blockIdx.x * 32, r0 = blockIdx.y * 32;
  int tx = threadIdx.x & 31, ty = threadIdx.x >> 5;
  #pragma unroll
  for (int i = 0; i < 32; i += 8)
    tile[ty + i][tx] = W[(size_t)(r0 + ty + i) * C + c0 + tx];
  __syncthreads();
  #pragma unroll
  for (int i = 0; i < 32; i += 8)
    WT[(size_t)(c0 + ty + i) * R + r0 + tx] = f2bf(tile[tx][ty + i]);
}

// ---------------------------------------------------------------------------
// 256x256-tile 8-phase pipelined GEMM: C[M][N](bf16) = A[M][K] * B[N][K]^T
// 512 thr (8 waves, warp grid 2Mx4N), BK=64, double-buffered 128KB LDS,
// st_16x32 XOR swizzle (SQ_LDS_BANK_CONFLICT == 0 measured).
// R10: XCD blockIdx swizzle removed (L3-fit regime).
__global__ __launch_bounds__(512, 2) void gemm256_bt(
    const unsigned short* __restrict__ A,
    const unsigned short* __restrict__ B,
    unsigned short* __restrict__ C, int M, int N, int K)
{
  __shared__ __attribute__((aligned(16))) unsigned short lds[65536]; // 128 KiB

  const int tid  = threadIdx.x;
  const int wave = tid >> 6, lane = tid & 63;
  const int quad = lane >> 4, l16 = lane & 15;
  const int wm8 = (wave >> 2) << 3;   // A-frag base (warp_m * 8)
  const int wn4 = (wave & 3) << 2;    // B-frag base (warp_n * 4)

  const int wg = blockIdx.x;          // no XCD swizzle (L3-fit)
  const int tm = M >> 8;
  const int m0 = (wg % tm) << 8;
  const int n0 = (wg / tm) << 8;

  // swizzled read offset (bytes) within a 1KB 16x32 subtile
  const int rd_off = ((l16 << 6) + (quad << 4)) ^ ((l16 >> 3) << 5);

  // staging source (inverse-swizzled global address) + LDS dest offset
  const int st_off = wave << 9;       // shorts: subtile (f*2+kb) = qi*8 + wave
  const int src_c  = ((wave & 1) << 5) + (((lane & 3) << 3) ^ ((lane >> 5) << 4));
  const unsigned short* Asrc = A + (size_t)(m0 + ((wave >> 1) << 4) + (lane >> 2)) * K + src_c;
  const unsigned short* Bsrc = B + (size_t)(n0 + ((wave >> 1) << 4) + (lane >> 2)) * K + src_c;

  const int NT = K >> 6;

#define STA(t, qi) GLD16(Asrc + (size_t)(qi) * 64 * K + (t) * 64, \
                         lds + (((t) & 1) << 15) + st_off + ((qi) << 12))
#define STB(t, qi) GLD16(Bsrc + (size_t)(qi) * 64 * K + (t) * 64, \
                         lds + (((t) & 1) << 15) + 16384 + st_off + ((qi) << 12))
#define RDA(dst, P)                                                            \
  _Pragma("unroll")                                                            \
  for (int j = 0; j < 2; ++j)                                                  \
    _Pragma("unroll")                                                          \
    for (int kb = 0; kb < 2; ++kb)                                             \
      dst[j][kb] = *(const bf16x8*)(Ar + ((((wm8 + 2 * (P) + j) << 1) | kb) << 10) + rd_off);
#define MMA(P, AF)                                                             \
  __builtin_amdgcn_s_setprio(1);                                               \
  _Pragma("unroll")                                                            \
  for (int j = 0; j < 2; ++j)                                                  \
    _Pragma("unroll")                                                          \
    for (int nf = 0; nf < 4; ++nf)                                             \
      _Pragma("unroll")                                                        \
      for (int kb = 0; kb < 2; ++kb)                                           \
        acc[2 * (P) + j][nf] = MFMA_BF16(AF[j][kb], b8[nf][kb], acc[2 * (P) + j][nf]); \
  __builtin_amdgcn_s_setprio(0);
#define LGKM4  asm volatile("s_waitcnt lgkmcnt(4)" ::: "memory");              \
               __builtin_amdgcn_sched_barrier(0)
#define LGKM0  asm volatile("s_waitcnt lgkmcnt(0)" ::: "memory");              \
               __builtin_amdgcn_sched_barrier(0)

  f32x4 acc[8][4];
  #pragma unroll
  for (int a = 0; a < 8; ++a)
    #pragma unroll
    for (int b = 0; b < 4; ++b)
      #pragma unroll
      for (int r = 0; r < 4; ++r) acc[a][b][r] = 0.f;

  // ---- prologue: tile 0 full (8 rounds) + tile 1 minus {Aq1,Aq3} (6) ----
  STB(0, 0); STB(0, 1); STB(0, 2); STB(0, 3);
  STA(0, 0); STA(0, 1); STA(0, 2); STA(0, 3);
  if (NT > 1) {
    STB(1, 0); STB(1, 1); STB(1, 2); STB(1, 3); STA(1, 0); STA(1, 2);
    asm volatile("s_waitcnt vmcnt(6)" ::: "memory");
  } else {
    asm volatile("s_waitcnt vmcnt(0)" ::: "memory");
  }
  __builtin_amdgcn_s_barrier();

  for (int u = 0; u < NT; ++u) {
    const char* Ar = (const char*)lds + ((u & 1) << 16);
    const char* Br = Ar + 32768;
    bf16x8 b8[4][2], aA[2][2], aB[2][2];
    // tile-top read group: all B-frags + P0 A-frags (drain under P0's wait)
    #pragma unroll
    for (int nf = 0; nf < 4; ++nf)
      #pragma unroll
      for (int kb = 0; kb < 2; ++kb)
        b8[nf][kb] = *(const bf16x8*)(Br + ((((wn4 + nf) << 1) | kb) << 10) + rd_off);
    RDA(aA, 0);
    __builtin_amdgcn_sched_barrier(0);   // group boundary for lgkm counting

    // ---- P0: issue P1 frags, stage, wait tile-top group, MFMA P0 ----
    RDA(aB, 1);
    if (u + 1 < NT) { STA(u + 1, 1); STA(u + 1, 3); }
    __builtin_amdgcn_s_barrier();
    LGKM4;
    MMA(0, aA);
    __builtin_amdgcn_s_barrier();

    // ---- P1: issue P2 frags, stage, wait P1 frags, MFMA P1 ----
    RDA(aA, 2);
    if (u + 2 < NT) { STB(u + 2, 0); STB(u + 2, 1); }
    __builtin_amdgcn_s_barrier();
    LGKM4;
    MMA(1, aB);
    __builtin_amdgcn_s_barrier();

    // ---- P2: issue P3 frags, stage, wait P2 frags, MFMA P2 ----
    RDA(aB, 3);
    if (u + 2 < NT) { STB(u + 2, 2); STA(u + 2, 0); }
    __builtin_amdgcn_s_barrier();
    LGKM4;
    MMA(2, aA);
    __builtin_amdgcn_s_barrier();

    // ---- P3: stage, wait P3 frags, MFMA P3, boundary vmcnt ----
    if (u + 2 < NT) { STB(u + 2, 3); STA(u + 2, 2); }
    __builtin_amdgcn_s_barrier();
    LGKM0;
    MMA(3, aB);
    if (u + 2 < NT) asm volatile("s_waitcnt vmcnt(6)" ::: "memory");
    else            asm volatile("s_waitcnt vmcnt(0)" ::: "memory");
    __builtin_amdgcn_s_barrier();
  }
#undef RDA
#undef MMA
#undef LGKM4
#undef LGKM0
#undef STA
#undef STB

  // ---- epilogue: bf16 store ----
  #pragma unroll
  for (int mt = 0; mt < 8; ++mt) {
    int row = m0 + ((wave >> 2) << 7) + mt * 16 + (quad << 2);
    #pragma unroll
    for (int nf = 0; nf < 4; ++nf) {
      int col = n0 + ((wave & 3) << 6) + nf * 16 + l16;
      #pragma unroll
      for (int r = 0; r < 4; ++r)
        C[(size_t)(row + r) * N + col] = f2bf(acc[mt][nf][r]);
    }
  }
}

// ---------------------------------------------------------------------------
// 128x256-tile 8-phase pipelined GEMM, fp32 out: C = A[M][K] * B[N][K]^T.
// For GEMM2 (M=4096, N=2048): grid 32x8 = 256 wgs = exactly 1 round. Frozen.
__global__ __launch_bounds__(512, 2) void gemm128x256_bt(
    const unsigned short* __restrict__ A,
    const unsigned short* __restrict__ B,
    float* __restrict__ C, int M, int N, int K)
{
  __shared__ __attribute__((aligned(16))) unsigned short lds[49152]; // 96 KiB

  const int tid  = threadIdx.x;
  const int wave = tid >> 6, lane = tid & 63;
  const int quad = lane >> 4, l16 = lane & 15;
  const int wm4 = (wave >> 2) << 2;   // A-frag base (0 or 4)
  const int wn4 = (wave & 3) << 2;    // B-frag base (0,4,8,12)

  int wg = blockIdx.x;
  if ((gridDim.x & 7) == 0) {
    int qq = (int)gridDim.x >> 3;
    wg = (wg & 7) * qq + (wg >> 3);
  }
  const int tm = M >> 7;
  const int m0 = (wg % tm) << 7;
  const int n0 = (wg / tm) << 8;

  const int rd_off = ((l16 << 6) + (quad << 4)) ^ ((l16 >> 3) << 5);
  const int st_off = wave << 9;       // shorts
  const int src_c  = ((wave & 1) << 5) + (((lane & 3) << 3) ^ ((lane >> 5) << 4));
  const unsigned short* Asrc = A + (size_t)(m0 + ((wave >> 1) << 4) + (lane >> 2)) * K + src_c;
  const unsigned short* Bsrc = B + (size_t)(n0 + ((wave >> 1) << 4) + (lane >> 2)) * K + src_c;

  const int NT = K >> 6;

#define STA(t, qi) GLD16(Asrc + (size_t)(qi) * 64 * K + (t) * 64, \
                         lds + (((t) & 1) * 24576) + st_off + ((qi) << 12))
#define STB(t, qi) GLD16(Bsrc + (size_t)(qi) * 64 * K + (t) * 64, \
                         lds + (((t) & 1) * 24576) + 8192 + st_off + ((qi) << 12))

  f32x4 acc[4][4];
  #pragma unroll
  for (int a = 0; a < 4; ++a)
    #pragma unroll
    for (int b = 0; b < 4; ++b)
      #pragma unroll
      for (int r = 0; r < 4; ++r) acc[a][b][r] = 0.f;

  // ---- prologue: tile 0 full (6 rounds) + tile 1 B (4 rounds) ----
  STB(0, 0); STB(0, 1); STB(0, 2); STB(0, 3);
  STA(0, 0); STA(0, 1);
  if (NT > 1) {
    STB(1, 0); STB(1, 1); STB(1, 2); STB(1, 3);
    asm volatile("s_waitcnt vmcnt(4)" ::: "memory");
  } else {
    asm volatile("s_waitcnt vmcnt(0)" ::: "memory");
  }
  __builtin_amdgcn_s_barrier();

  for (int u = 0; u < NT; ++u) {
    const char* Ar = (const char*)lds + (u & 1) * 49152;
    const char* Br = Ar + 16384;
    bf16x8 b8[4][2], aA[2][2], aB[2][2];
    // tile-top: all 8 B-frags + Pa's 4 A-frags (drain at Pa's lgkmcnt(4))
    #pragma unroll
    for (int nf = 0; nf < 4; ++nf)
      #pragma unroll
      for (int kb = 0; kb < 2; ++kb)
        b8[nf][kb] = *(const bf16x8*)(Br + ((((wn4 + nf) << 1) | kb) << 10) + rd_off);
    #pragma unroll
    for (int j = 0; j < 2; ++j)
      #pragma unroll
      for (int kb = 0; kb < 2; ++kb)
        aA[j][kb] = *(const bf16x8*)(Ar + ((((wm4 + j) << 1) | kb) << 10) + rd_off);
    __builtin_amdgcn_sched_barrier(0);

    // ---- Pa: issue Pb A-frags, stage A(u+1), wait top group, 16 MFMA ----
    #pragma unroll
    for (int j = 0; j < 2; ++j)
      #pragma unroll
      for (int kb = 0; kb < 2; ++kb)
        aB[j][kb] = *(const bf16x8*)(Ar + ((((wm4 + 2 + j) << 1) | kb) << 10) + rd_off);
    if (u + 1 < NT) { STA(u + 1, 0); STA(u + 1, 1); }
    __builtin_amdgcn_s_barrier();
    asm volatile("s_waitcnt lgkmcnt(4)" ::: "memory");
    __builtin_amdgcn_sched_barrier(0);
    __builtin_amdgcn_s_setprio(1);
    #pragma unroll
    for (int j = 0; j < 2; ++j)
      #pragma unroll
      for (int nf = 0; nf < 4; ++nf)
        #pragma unroll
        for (int kb = 0; kb < 2; ++kb)
          acc[j][nf] = MFMA_BF16(aA[j][kb], b8[nf][kb], acc[j][nf]);
    __builtin_amdgcn_s_setprio(0);
    __builtin_amdgcn_s_barrier();

    // ---- Pb: stage B(u+2), wait Pb A-frags, 16 MFMA, boundary vmcnt ----
    if (u + 2 < NT) { STB(u + 2, 0); STB(u + 2, 1); STB(u + 2, 2); STB(u + 2, 3); }
    __builtin_amdgcn_s_barrier();
    asm volatile("s_waitcnt lgkmcnt(0)" ::: "memory");
    __builtin_amdgcn_sched_barrier(0);
    __builtin_amdgcn_s_setprio(1);
    #pragma unroll
    for (int j = 0; j < 2; ++j)
      #pragma unroll
      for (int nf = 0; nf < 4; ++nf)
        #pragma unroll
        for (int kb = 0; kb < 2; ++kb)
          acc[2 + j][nf] = MFMA_BF16(aB[j][kb], b8[nf][kb], acc[2 + j][nf]);
    __builtin_amdgcn_s_setprio(0);
    if (u + 2 < NT) asm volatile("s_waitcnt vmcnt(4)" ::: "memory");
    else            asm volatile("s_waitcnt vmcnt(0)" ::: "memory");
    __builtin_amdgcn_s_barrier();
  }
#undef STA
#undef STB

  // ---- epilogue: fp32 store ----
  #pragma unroll
  for (int mt = 0; mt < 4; ++mt) {
    int row = m0 + ((wave >> 2) << 6) + mt * 16 + (quad << 2);
    #pragma unroll
    for (int nf = 0; nf < 4; ++nf) {
      int col = n0 + ((wave & 3) << 6) + nf * 16 + l16;
      #pragma unroll
      for (int r = 0; r < 4; ++r)
        C[(size_t)(row + r) * N + col] = acc[mt][nf][r];
    }
  }
}

// ---------------------------------------------------------------------------
// ba = H @ W_ba (fp32), beta = sigmoid(b), g = -exp(A_log)*softplus(a+dt_bias)
// R10: grid 1024 (1 row/wave -> 16 waves/CU, 4x TLP) + float4 H loads.
__global__ __launch_bounds__(256) void ba_kernel(
    const float* __restrict__ H, const float* __restrict__ Wba,
    const float* __restrict__ dtb, const float* __restrict__ Alog,
    float* __restrict__ bbuf, float* __restrict__ gbuf)
{
  int t = threadIdx.x;
  int col = t & 63, wv = t >> 6;
  int m = blockIdx.x * 4 + wv;
  const float* h0 = H + (size_t)m * 2048;
  float acc = 0.f;
  for (int k = 0; k < 2048; k += 4) {
    float4 hv = *(const float4*)(h0 + k);
    acc += hv.x * Wba[(k + 0) * 64 + col];
    acc += hv.y * Wba[(k + 1) * 64 + col];
    acc += hv.z * Wba[(k + 2) * 64 + col];
    acc += hv.w * Wba[(k + 3) * 64 + col];
  }
  int b = m >> 11, s = m & 2047;
  if (col < 32) {
    bbuf[((size_t)(b * 32 + col)) * 2048 + s] = 1.f / (1.f + __expf(-acc));
  } else {
    int hh = col - 32;
    float x  = acc + dtb[hh];
    float sp = (x > 20.f) ? x : log1pf(__expf(x));
    gbuf[((size_t)(b * 32 + hh)) * 2048 + s] = -__expf(Alog[hh]) * sp;
  }
}

// ---------------------------------------------------------------------------
// causal depthwise conv (K=4) + silu + (q,k) l2-norm (q also * DK^-0.5)
// R9: vectorized — 8 cols/thread (bf16x8 16B loads/stores), 16 thr/head,
// 8 heads per 128-thr block, grid (1024, 8). Norm reduce = in-wave 16-lane
// shfl_xor (no LDS, no syncthreads).
__global__ __launch_bounds__(128) void conv_kernel(
    const unsigned short* __restrict__ qkvz, const float* __restrict__ cw,
    unsigned short* __restrict__ qn, unsigned short* __restrict__ kn,
    unsigned short* __restrict__ vb)
{
  int s_base = blockIdx.x * 4;
  int head   = blockIdx.y * 8 + (threadIdx.x >> 4);
  int c8     = (threadIdx.x & 15) * 8;
  int col    = head * 128 + c8;
  int s_loc  = s_base & 2047;

  float vin[7][8];
  #pragma unroll
  for (int t = 0; t < 7; ++t) {
    int sp = s_loc + t - 3;
    if (sp >= 0) {
      bf16x8 v = *(const bf16x8*)(qkvz + (size_t)(s_base + t - 3) * 12288 + col);
      #pragma unroll
      for (int j = 0; j < 8; ++j) vin[t][j] = bf2f((unsigned short)v[j]);
    } else {
      #pragma unroll
      for (int j = 0; j < 8; ++j) vin[t][j] = 0.f;
    }
  }
  float w[8][4];
  #pragma unroll
  for (int j = 0; j < 8; ++j) {
    float4 wv = *(const float4*)(cw + (size_t)(col + j) * 4);
    w[j][0] = wv.x; w[j][1] = wv.y; w[j][2] = wv.z; w[j][3] = wv.w;
  }
  float y[4][8];
  #pragma unroll
  for (int u = 0; u < 4; ++u)
    #pragma unroll
    for (int j = 0; j < 8; ++j) {
      float acc = vin[u][j]*w[j][0] + vin[u+1][j]*w[j][1]
                + vin[u+2][j]*w[j][2] + vin[u+3][j]*w[j][3];
      y[u][j] = acc / (1.f + __expf(-acc));
    }

  if (head < 32) {
    #pragma unroll
    for (int u = 0; u < 4; ++u) {
      float ss = 0.f;
      #pragma unroll
      for (int j = 0; j < 8; ++j) ss += y[u][j] * y[u][j];
      ss += __shfl_xor(ss, 1);
      ss += __shfl_xor(ss, 2);
      ss += __shfl_xor(ss, 4);
      ss += __shfl_xor(ss, 8);
      float r = rsqrtf(ss + 1e-6f);
      bf16x8 out;
      if (head < 16) {
        float rq = r * 0.08838834764831845f;
        #pragma unroll
        for (int j = 0; j < 8; ++j) out[j] = (short)f2bf(y[u][j] * rq);
        *(bf16x8*)(qn + ((size_t)(s_base + u) * 16 + head) * 128 + c8) = out;
      } else {
        #pragma unroll
        for (int j = 0; j < 8; ++j) out[j] = (short)f2bf(y[u][j] * r);
        *(bf16x8*)(kn + ((size_t)(s_base + u) * 16 + (head - 16)) * 128 + c8) = out;
      }
    }
  } else {
    #pragma unroll
    for (int u = 0; u < 4; ++u) {
      bf16x8 out;
      #pragma unroll
      for (int j = 0; j < 8; ++j) out[j] = (short)f2bf(y[u][j]);
      *(bf16x8*)(vb + ((size_t)(s_base + u) * 32 + (head - 32)) * 128 + c8) = out;
    }
  }
}

// ---------------------------------------------------------------------------
// per-chunk: A=(beta k)k^T * decay (strict lower), attn=q k^T * decay,
// register-column forward substitution (no barriers), outputs packed for scan.
__global__ __launch_bounds__(256) void chunk_kernel(
    const unsigned short* __restrict__ qnb, const unsigned short* __restrict__ knb,
    const unsigned short* __restrict__ vbb,
    const float* __restrict__ gbuf, const float* __restrict__ bbuf,
    unsigned short* __restrict__ attnb, unsigned short* __restrict__ vadjb,
    unsigned short* __restrict__ kcdn, unsigned short* __restrict__ qgb,
    unsigned short* __restrict__ kdT, float* __restrict__ egl)
{
  int cid = blockIdx.x;
  int n = cid & 31, h = (cid >> 5) & 31, b = cid >> 10;
  int h2 = h >> 1, s0 = n * 64;
  int gs0 = b * 2048 + s0;
  int tid = threadIdx.x, wave = tid >> 6, lane = tid & 63, quad = lane >> 4, l16 = lane & 15;

  __shared__ __attribute__((aligned(16))) unsigned short kS[64 * 136]; // bf16 k tile
  __shared__ __attribute__((aligned(16))) float As[64 * 68];           // fp32 A (strict lower)
  __shared__ float gcS[64], betaS[64];
  __shared__ float rsV[64], rsK[64], egq[64], egliS[64];

  if (tid < 64) {
    gcS[tid]   = gbuf[((size_t)(b * 32 + h)) * 2048 + s0 + tid];
    betaS[tid] = bbuf[((size_t)(b * 32 + h)) * 2048 + s0 + tid];
  }
  {                               // stage k tile -> LDS (bf16 copy)
    int i = tid >> 2, seg = tid & 3;
    const bf16x8* kp = (const bf16x8*)(knb + ((size_t)(gs0 + i) * 16 + h2) * 128 + seg * 32);
    bf16x8* kd_ = (bf16x8*)(kS + i * 136 + seg * 32);
    #pragma unroll
    for (int u = 0; u < 4; ++u) kd_[u] = kp[u];
  }
  __syncthreads();                // B1: gcS/betaS/kS staged
  if (tid == 0) {                 // inclusive cumsum of g
    float run = 0.f;
    for (int i = 0; i < 64; ++i) { run += gcS[i]; gcS[i] = run; }
  }
  __syncthreads();                // B2: cumsum done

  if (tid < 64) {                 // per-row scales (concurrent with phase 1)
    float gi = gcS[tid];
    rsV[tid]   = betaS[tid];
    rsK[tid]   = betaS[tid] * __expf(gi);
    egq[tid]   = __expf(gi);
    egliS[tid] = __expf(gcS[63] - gi);
    if (tid == 0) egl[cid] = __expf(gcS[63]);
  }

  // phase 1: A and attn via MFMA (wave w owns i-tile w)
  {
    int arow = wave * 16 + l16;
    float bscale = betaS[arow];
    const unsigned short* qpg = qnb + ((size_t)(gs0 + arow) * 16 + h2) * 128;
    bf16x8 kbf[4], qf[4];
    #pragma unroll
    for (int ks = 0; ks < 4; ++ks) {
      bf16x8 kfr = *(const bf16x8*)(kS + arow * 136 + ks * 32 + quad * 8);
      bf16x8 t;
      #pragma unroll
      for (int e = 0; e < 8; ++e)
        t[e] = (short)f2bf(bf2f((unsigned short)kfr[e]) * bscale);
      kbf[ks] = t;
      qf[ks] = *(const bf16x8*)(qpg + ks * 32 + quad * 8);
    }
    #pragma unroll
    for (int jt = 0; jt < 4; ++jt) {
      f32x4 accA, accQ;
      #pragma unroll
      for (int r = 0; r < 4; ++r) { accA[r] = 0.f; accQ[r] = 0.f; }
      #pragma unroll
      for (int ks = 0; ks < 4; ++ks) {
        bf16x8 bfr = *(const bf16x8*)(kS + (jt * 16 + l16) * 136 + ks * 32 + quad * 8);
        accA = MFMA_BF16(kbf[ks], bfr, accA);
        accQ = MFMA_BF16(qf[ks],  bfr, accQ);
      }
      #pragma unroll
      for (int r = 0; r < 4; ++r) {
        int i = wave * 16 + quad * 4 + r;
        int j = jt * 16 + l16;
        float e = __expf(gcS[i] - gcS[j]);
        As[i * 68 + j] = (j < i) ? (accA[r] * e) : 0.f;
        attnb[(size_t)cid * 4096 + i * 64 + j] = (j <= i) ? f2bf(accQ[r] * e) : (unsigned short)0;
      }
    }
  }
  __syncthreads();                // B3: As + rs arrays ready

  // phase 2+3: per-thread register column + blocked forward substitution.
  // thread c<128 owns v-column c; thread c>=128 owns k-column c-128.
  {
    int c = tid;
    float x[64];
    if (c < 128) {
      const unsigned short* vp = vbb + ((size_t)gs0 * 32 + h) * 128 + c;
      #pragma unroll
      for (int i = 0; i < 64; ++i)
        x[i] = bf2f(vp[(size_t)i * 4096]) * rsV[i];
    } else {
      int ck = c - 128;
      #pragma unroll
      for (int i = 0; i < 64; ++i)
        x[i] = bf2f(kS[i * 136 + ck]) * rsK[i];
    }
    // blocked forward substitution: As strict-lower (zeros on/above diag make
    // full 16-wide row updates safe).
    #pragma unroll
    for (int bi = 0; bi < 4; ++bi) {
      const int base = bi * 16;
      // serial in-block rows
      #pragma unroll
      for (int ii = 1; ii < 16; ++ii) {
        const int r = base + ii;
        const f32x4* ar = (const f32x4*)(As + r * 68 + base);
        float s = 0.f;
        #pragma unroll
        for (int g = 0; g < 4; ++g) {
          f32x4 a4 = ar[g];
          s += a4[0] * x[base + g*4] + a4[1] * x[base + g*4 + 1]
             + a4[2] * x[base + g*4 + 2] + a4[3] * x[base + g*4 + 3];
        }
        x[r] -= s;
      }
      // batch update of rows below this block
      #pragma unroll
      for (int r = base + 16; r < 64; ++r) {
        const f32x4* ar = (const f32x4*)(As + r * 68 + base);
        float s = 0.f;
        #pragma unroll
        for (int g = 0; g < 4; ++g) {
          f32x4 a4 = ar[g];
          s += a4[0] * x[base + g*4] + a4[1] * x[base + g*4 + 1]
             + a4[2] * x[base + g*4 + 2] + a4[3] * x[base + g*4 + 3];
        }
        x[r] -= s;
      }
    }
    // column store: vadj (c<128) / negated kcd (c>=128), coalesced 2B stores
    if (c < 128) {
      unsigned short* vo = vadjb + (size_t)cid * 8192 + c;
      #pragma unroll
      for (int i = 0; i < 64; ++i) vo[i * 128] = f2bf(x[i]);
    } else {
      unsigned short* ko = kcdn + (size_t)cid * 8192 + (c - 128);
      #pragma unroll
      for (int i = 0; i < 64; ++i) ko[i * 128] = f2bf(-x[i]);
    }
  }

  // phase 4: pack qg (q * e^gc) and kdT (k * e^(g_last - gc), transposed)
  {
    int i = tid >> 2, seg = tid & 3;
    float egli = egliS[i];
    float eqi  = egq[i];
    size_t base128 = (size_t)cid * 8192 + i * 128 + seg * 32;
    const unsigned short* qp = qnb + ((size_t)(gs0 + i) * 16 + h2) * 128 + seg * 32;
    #pragma unroll
    for (int u = 0; u < 32; u += 4) {
      *(unsigned long long*)(qgb + base128 + u) =
          pack4bf(bf2f(qp[u]) * eqi, bf2f(qp[u+1]) * eqi, bf2f(qp[u+2]) * eqi, bf2f(qp[u+3]) * eqi);
    }
    const unsigned short* kp = kS + i * 136 + seg * 32;
    unsigned short* kdo = kdT + (size_t)cid * 8192;
    #pragma unroll
    for (int u = 0; u < 32; ++u) {
      int d = seg * 32 + u;
      kdo[(size_t)d * 64 + i] = f2bf(bf2f(kp[u]) * egli);
    }
  }
}

// ---------------------------------------------------------------------------
// sequential scan over 32 chunks. grid (64 bh, 4 dv-slices of 32).
// R8: register prefetch; R10: deepened to 3 sets (loads ~2 chunks ahead).
struct ScanPref {
  bf16x8 kf[4], qf[4], af2[2], kdf[2][2];
  float  vinit[2][4];
  float  a;
};

__device__ __forceinline__ void scan_load(
    ScanPref& p, size_t cid,
    const unsigned short* __restrict__ qgb, const unsigned short* __restrict__ kcdn,
    const unsigned short* __restrict__ attnb, const unsigned short* __restrict__ kdT,
    const unsigned short* __restrict__ vadjb, const float* __restrict__ egl,
    int w, int quad, int l16, int dv0)
{
  const unsigned short* qgc = qgb  + cid * 8192;
  const unsigned short* kcc = kcdn + cid * 8192;
  const unsigned short* atc = attnb + cid * 4096;
  const unsigned short* kdc = kdT  + cid * 8192;
  const unsigned short* vac = vadjb + cid * 8192;
  p.a = egl[cid];
  #pragma unroll
  for (int ks = 0; ks < 4; ++ks) {
    p.kf[ks] = *(const bf16x8*)(kcc + (size_t)(w * 16 + l16) * 128 + ks * 32 + quad * 8);
    p.qf[ks] = *(const bf16x8*)(qgc + (size_t)(w * 16 + l16) * 128 + ks * 32 + quad * 8);
  }
  #pragma unroll
  for (int k2 = 0; k2 < 2; ++k2)
    p.af2[k2] = *(const bf16x8*)(atc + (size_t)(w * 16 + l16) * 64 + k2 * 32 + quad * 8);
  #pragma unroll
  for (int mi = 0; mi < 2; ++mi)
    #pragma unroll
    for (int k2 = 0; k2 < 2; ++k2)
      p.kdf[mi][k2] = *(const bf16x8*)(kdc + (size_t)((w * 2 + mi) * 16 + l16) * 64 + k2 * 32 + quad * 8);
  #pragma unroll
  for (int ni = 0; ni < 2; ++ni)
    #pragma unroll
    for (int r = 0; r < 4; ++r)
      p.vinit[ni][r] = bf2f(vac[(size_t)(w * 16 + quad * 4 + r) * 128 + dv0 + ni * 16 + l16]);
}

__device__ __forceinline__ void scan_step(
    const ScanPref& p, f32x4 st[2][2],
    unsigned short* stT, unsigned short* vnT,
    unsigned short* __restrict__ obuf, int bh, int n,
    int w, int quad, int l16, int dv0)
{
  bf16x8 sf[2][4];
  #pragma unroll
  for (int ni = 0; ni < 2; ++ni)
    #pragma unroll
    for (int ks = 0; ks < 4; ++ks)
      sf[ni][ks] = *(const bf16x8*)(stT + (ni * 16 + l16) * 136 + ks * 32 + quad * 8);

  // v_new = v_adj - kcd @ state  (kcd stored negated)
  f32x4 vacc[2];
  #pragma unroll
  for (int ni = 0; ni < 2; ++ni)
    #pragma unroll
    for (int r = 0; r < 4; ++r) vacc[ni][r] = p.vinit[ni][r];
  #pragma unroll
  for (int ni = 0; ni < 2; ++ni)
    #pragma unroll
    for (int ks = 0; ks < 4; ++ks)
      vacc[ni] = MFMA_BF16(p.kf[ks], sf[ni][ks], vacc[ni]);

  // o (part1) = (q e^gc) @ state
  f32x4 oacc[2];
  #pragma unroll
  for (int ni = 0; ni < 2; ++ni)
    #pragma unroll
    for (int r = 0; r < 4; ++r) oacc[ni][r] = 0.f;
  #pragma unroll
  for (int ni = 0; ni < 2; ++ni)
    #pragma unroll
    for (int ks = 0; ks < 4; ++ks)
      oacc[ni] = MFMA_BF16(p.qf[ks], sf[ni][ks], oacc[ni]);

  // publish v_new^T
  #pragma unroll
  for (int ni = 0; ni < 2; ++ni)
    #pragma unroll
    for (int r = 0; r < 4; ++r)
      vnT[(ni * 16 + l16) * 72 + w * 16 + quad * 4 + r] = f2bf(vacc[ni][r]);
  __syncthreads();

  // o (part2) += attn @ v_new ; store o (bf16)
  bf16x8 vf[2][2];
  #pragma unroll
  for (int ni = 0; ni < 2; ++ni)
    #pragma unroll
    for (int k2 = 0; k2 < 2; ++k2)
      vf[ni][k2] = *(const bf16x8*)(vnT + (ni * 16 + l16) * 72 + k2 * 32 + quad * 8);
  #pragma unroll
  for (int ni = 0; ni < 2; ++ni)
    #pragma unroll
    for (int k2 = 0; k2 < 2; ++k2)
      oacc[ni] = MFMA_BF16(p.af2[k2], vf[ni][k2], oacc[ni]);
  unsigned short* op = obuf + ((size_t)bh * 2048 + n * 64) * 128;
  #pragma unroll
  for (int ni = 0; ni < 2; ++ni)
    #pragma unroll
    for (int r = 0; r < 4; ++r)
      op[(size_t)(w * 16 + quad * 4 + r) * 128 + dv0 + ni * 16 + l16] = f2bf(oacc[ni][r]);

  // state = a*state + kdT @ v_new  (fp32 master in regs)
  #pragma unroll
  for (int mi = 0; mi < 2; ++mi) {
    #pragma unroll
    for (int ni = 0; ni < 2; ++ni) {
      f32x4 acc_;
      #pragma unroll
      for (int r = 0; r < 4; ++r) acc_[r] = p.a * st[mi][ni][r];
      #pragma unroll
      for (int k2 = 0; k2 < 2; ++k2)
        acc_ = MFMA_BF16(p.kdf[mi][k2], vf[ni][k2], acc_);
      st[mi][ni] = acc_;
    }
  }
  // publish state^T bf16 for next chunk
  #pragma unroll
  for (int mi = 0; mi < 2; ++mi)
    #pragma unroll
    for (int ni = 0; ni < 2; ++ni)
      #pragma unroll
      for (int r = 0; r < 4; ++r)
        stT[(ni * 16 + l16) * 136 + (w * 2 + mi) * 16 + quad * 4 + r] = f2bf(st[mi][ni][r]);
  __syncthreads();
}

__global__ __launch_bounds__(256, 1) void scan_kernel(
    const unsigned short* __restrict__ qgb, const unsigned short* __restrict__ kcdn,
    const unsigned short* __restrict__ attnb, const unsigned short* __restrict__ kdT,
    const unsigned short* __restrict__ vadjb, const float* __restrict__ egl,
    unsigned short* __restrict__ obuf)
{
  int bh = blockIdx.x, dv0 = blockIdx.y * 32;
  int tid = threadIdx.x, w = tid >> 6, quad = (tid & 63) >> 4, l16 = tid & 15;
  __shared__ __attribute__((aligned(16))) unsigned short stT[32 * 136];
  __shared__ __attribute__((aligned(16))) unsigned short vnT[32 * 72];

  for (int idx = tid; idx < 32 * 136; idx += 256) stT[idx] = 0;
  f32x4 st[2][2];
  #pragma unroll
  for (int a = 0; a < 2; ++a)
    #pragma unroll
    for (int bq = 0; bq < 2; ++bq)
      #pragma unroll
      for (int r = 0; r < 4; ++r) st[a][bq][r] = 0.f;

  size_t base = (size_t)bh * 32;
  ScanPref pA, pB, pC;
  scan_load(pA, base + 0, qgb, kcdn, attnb, kdT, vadjb, egl, w, quad, l16, dv0);
  scan_load(pB, base + 1, qgb, kcdn, attnb, kdT, vadjb, egl, w, quad, l16, dv0);
  scan_load(pC, base + 2, qgb, kcdn, attnb, kdT, vadjb, egl, w, quad, l16, dv0);
  __syncthreads();

  for (int n = 0; n < 32; n += 3) {
    scan_step(pA, st, stT, vnT, obuf, bh, n, w, quad, l16, dv0);
    if (n + 3 < 32)
      scan_load(pA, base + n + 3, qgb, kcdn, attnb, kdT, vadjb, egl, w, quad, l16, dv0);
    if (n + 1 < 32) {
      scan_step(pB, st, stT, vnT, obuf, bh, n + 1, w, quad, l16, dv0);
      if (n + 4 < 32)
        scan_load(pB, base + n + 4, qgb, kcdn, attnb, kdT, vadjb, egl, w, quad, l16, dv0);
    }
    if (n + 2 < 32) {
      scan_step(pC, st, stT, vnT, obuf, bh, n + 2, w, quad, l16, dv0);
      if (n + 5 < 32)
        scan_load(pC, base + n + 5, qgb, kcdn, attnb, kdT, vadjb, egl, w, quad, l16, dv0);
    }
  }
}

// ---------------------------------------------------------------------------
// gated RMSNorm: rmsnorm(o)*w*silu(z) -> gated bf16.
// R9: vectorized — 8 elems/thread (bf16x8), 16 thr/row, 16 rows per
// 256-thr block, grid 8192. Reduce = in-wave 16-lane shfl_xor.
__global__ __launch_bounds__(256) void gate_kernel(
    const unsigned short* __restrict__ obuf, const unsigned short* __restrict__ qkvz,
    const float* __restrict__ nw, unsigned short* __restrict__ gated)
{
  int id = blockIdx.x * 16 + (threadIdx.x >> 4);  // (b*2048+s)*32 + h
  int h = id & 31, bs = id >> 5;
  int b = bs >> 11, s = bs & 2047;
  int c8 = (threadIdx.x & 15) * 8;
  const unsigned short* op = obuf + (((size_t)(b * 32 + h)) * 2048 + s) * 128 + c8;
  const unsigned short* zp = qkvz + (size_t)bs * 12288 + 8192 + h * 128 + c8;

  bf16x8 xv = *(const bf16x8*)op;
  float x[8];
  float ss = 0.f;
  #pragma unroll
  for (int j = 0; j < 8; ++j) { x[j] = bf2f((unsigned short)xv[j]); ss += x[j] * x[j]; }
  ss += __shfl_xor(ss, 1);
  ss += __shfl_xor(ss, 2);
  ss += __shfl_xor(ss, 4);
  ss += __shfl_xor(ss, 8);
  float r = rsqrtf(ss * (1.f / 128.f) + 1e-6f);

  bf16x8 zv = *(const bf16x8*)zp;
  float4 nw0 = *(const float4*)(nw + c8);
  float4 nw1 = *(const float4*)(nw + c8 + 4);
  float nwv[8] = {nw0.x, nw0.y, nw0.z, nw0.w, nw1.x, nw1.y, nw1.z, nw1.w};
  bf16x8 out;
  #pragma unroll
  for (int j = 0; j < 8; ++j) {
    float z = bf2f((unsigned short)zv[j]);
    float g = z / (1.f + __expf(-z));
    out[j] = (short)f2bf(x[j] * r * nwv[j] * g);
  }
  *(bf16x8*)(gated + (size_t)bs * 4096 + h * 128 + c8) = out;
}

// ---------------------------------------------------------------------------
extern "C" void kernel_launch(void* const* d_in, const int* in_sizes, int n_in,
                              void* d_out, int out_size, void* d_ws, size_t ws_size,
                              hipStream_t stream)
{
  const float* H     = (const float*)d_in[0];
  const float* Wqkvz = (const float*)d_in[1];
  const float* Wba   = (const float*)d_in[2];
  const float* cw    = (const float*)d_in[3];
  const float* dtb   = (const float*)d_in[4];
  const float* Alog  = (const float*)d_in[5];
  const float* nw    = (const float*)d_in[6];
  const float* Wout  = (const float*)d_in[7];
  float* out = (float*)d_out;

  // ---- workspace arena (370,155,520 B) with aliasing ----
  const size_t U1 = 0;                      //  67,108,864: Hbf+WqT -> qn+kn+vb
  const size_t U2 = U1 + 67108864;          // 100,663,296: qkvz bf16 (z until gate)
  const size_t U3 = U2 + 100663296;         //  16,777,216: WoT
  const size_t U4 = U3 + 16777216;          //   1,048,576: bbuf+gbuf
  const size_t U5 = U4 + 1048576;           // 151,003,136: chunk outputs -> gated
  const size_t U6 = U5 + 151003136;         //  33,554,432: obuf bf16
  const size_t NEED = U6 + 33554432;        // 370,155,520
  if (ws_size < NEED) return;               // graceful fail (diagnostic)

  char* base = (char*)d_ws;
  unsigned short* Hbf   = (unsigned short*)(base + U1);
  unsigned short* WqT   = (unsigned short*)(base + U1 + 16777216);
  unsigned short* qnb   = (unsigned short*)(base + U1);              // after GEMM1
  unsigned short* knb   = (unsigned short*)(base + U1 + 16777216);   // after GEMM1
  unsigned short* vbb   = (unsigned short*)(base + U1 + 33554432);   // after GEMM1
  unsigned short* qkvzb = (unsigned short*)(base + U2);
  unsigned short* WoT   = (unsigned short*)(base + U3);
  float*          bbuf  = (float*)(base + U4);
  float*          gbuf  = (float*)(base + U4 + 524288);
  unsigned short* attnb = (unsigned short*)(base + U5);
  unsigned short* vadjb = (unsigned short*)(base + U5 + 16777216);
  unsigned short* kcdn  = (unsigned short*)(base + U5 + 50331648);
  unsigned short* qgb   = (unsigned short*)(base + U5 + 83886080);
  unsigned short* kdTb  = (unsigned short*)(base + U5 + 117440512);
  float*          egl   = (float*)(base + U5 + 150994944);
  unsigned short* gated = (unsigned short*)(base + U5);              // after scan
  unsigned short* obuf  = (unsigned short*)(base + U6);

  cast_bf16_kernel<<<8192, 256, 0, stream>>>(H, Hbf, 4096 * 2048);
  transpose_cast_kernel<<<dim3(12288 / 32, 2048 / 32), 256, 0, stream>>>(Wqkvz, WqT, 2048, 12288);
  transpose_cast_kernel<<<dim3(2048 / 32, 4096 / 32), 256, 0, stream>>>(Wout, WoT, 4096, 2048);
  // GEMM1: 4096x12288x2048 -> 16x48 = 768 workgroups of 512 thr (256^2 tiles)
  gemm256_bt<<<768, 512, 0, stream>>>(Hbf, WqT, qkvzb, 4096, 12288, 2048);
  ba_kernel<<<1024, 256, 0, stream>>>(H, Wba, dtb, Alog, bbuf, gbuf);
  conv_kernel<<<dim3(1024, 8), 128, 0, stream>>>(qkvzb, cw, qnb, knb, vbb);
  chunk_kernel<<<2048, 256, 0, stream>>>(qnb, knb, vbb, gbuf, bbuf, attnb, vadjb, kcdn, qgb, kdTb, egl);
  scan_kernel<<<dim3(64, 4), 256, 0, stream>>>(qgb, kcdn, attnb, kdTb, vadjb, egl, obuf);
  gate_kernel<<<8192, 256, 0, stream>>>(obuf, qkvzb, nw, gated);
  // GEMM2: 4096x2048x4096 -> 32x8 = 256 workgroups of 512 thr (128x256 tiles)
  gemm128x256_bt<<<256, 512, 0, stream>>>(gated, WoT, out, 4096, 2048, 4096);
}

// Round 9
// 851.245 us; speedup vs baseline: 1.0222x; 1.0222x over previous
//
#include <hip/hip_runtime.h>
#include <hip/hip_bf16.h>

// ---------------------------------------------------------------------------
// Qwen3.5 GatedDeltaNet forward, MI355X (gfx950)
// B=2 S=2048 HIDDEN=2048 HK=16 HV=32 DK=DV=128 KCONV=4 CHUNK=64
// R10->R11: A/B isolation of the R10 regression (+18 us, same-clock).
// scan_kernel reverted to the PROVEN depth-2 register prefetch (R8/R6 form:
// unconditional loads, no guarded writes to big register structs — depth-3's
// conditional rotation was the suspected codegen regression). ba_kernel
// keeps R10's 4x-TLP form (mechanism-neutral-to-positive); gemm256 keeps
// no-XCD-swizzle (measured neutral in top-5, L3-fit regime).
// Workspace: 370,155,520 B with region aliasing (see kernel_launch).
// ---------------------------------------------------------------------------

typedef short bf16x8 __attribute__((ext_vector_type(8)));
typedef float f32x4  __attribute__((ext_vector_type(4)));

#define MFMA_BF16(a,b,c) __builtin_amdgcn_mfma_f32_16x16x32_bf16((a),(b),(c),0,0,0)
#define GLD16(g,l) __builtin_amdgcn_global_load_lds((const __attribute__((address_space(1))) void*)(g), (__attribute__((address_space(3))) void*)(l), 16, 0, 0)

__device__ __forceinline__ unsigned short f2bf(float x){
  union { float f; unsigned u; } v; v.f = x;
  return (unsigned short)((v.u + 0x7fffu + ((v.u >> 16) & 1u)) >> 16);
}
__device__ __forceinline__ float bf2f(unsigned short h){
  union { unsigned u; float f; } v; v.u = ((unsigned)h) << 16; return v.f;
}
__device__ __forceinline__ unsigned long long pack4bf(float a, float b, float c, float d){
  return (unsigned long long)f2bf(a) | ((unsigned long long)f2bf(b) << 16)
       | ((unsigned long long)f2bf(c) << 32) | ((unsigned long long)f2bf(d) << 48);
}

// ---------------------------------------------------------------------------
__global__ __launch_bounds__(256) void cast_bf16_kernel(
    const float* __restrict__ in, unsigned short* __restrict__ out, int n)
{
  int i = (blockIdx.x * 256 + threadIdx.x) * 4;
  if (i >= n) return;
  float4 v = *(const float4*)(in + i);
  *(unsigned long long*)(out + i) = pack4bf(v.x, v.y, v.z, v.w);
}

// transpose + cast: W[R][C] f32 -> WT[C][R] bf16
__global__ __launch_bounds__(256) void transpose_cast_kernel(
    const float* __restrict__ W, unsigned short* __restrict__ WT, int R, int C)
{
  __shared__ __attribute__((aligned(16))) float tile[32][33];
  int c0 = blockIdx.x * 32, r0 = blockIdx.y * 32;
  int tx = threadIdx.x & 31, ty = threadIdx.x >> 5;
  #pragma unroll
  for (int i = 0; i < 32; i += 8)
    tile[ty + i][tx] = W[(size_t)(r0 + ty + i) * C + c0 + tx];
  __syncthreads();
  #pragma unroll
  for (int i = 0; i < 32; i += 8)
    WT[(size_t)(c0 + ty + i) * R + r0 + tx] = f2bf(tile[tx][ty + i]);
}

// ---------------------------------------------------------------------------
// 256x256-tile 8-phase pipelined GEMM: C[M][N](bf16) = A[M][K] * B[N][K]^T
// 512 thr (8 waves, warp grid 2Mx4N), BK=64, double-buffered 128KB LDS,
// st_16x32 XOR swizzle (SQ_LDS_BANK_CONFLICT == 0 measured). No XCD
// swizzle (L3-fit regime; measured neutral). Frozen.
__global__ __launch_bounds__(512, 2) void gemm256_bt(
    const unsigned short* __restrict__ A,
    const unsigned short* __restrict__ B,
    unsigned short* __restrict__ C, int M, int N, int K)
{
  __shared__ __attribute__((aligned(16))) unsigned short lds[65536]; // 128 KiB

  const int tid  = threadIdx.x;
  const int wave = tid >> 6, lane = tid & 63;
  const int quad = lane >> 4, l16 = lane & 15;
  const int wm8 = (wave >> 2) << 3;   // A-frag base (warp_m * 8)
  const int wn4 = (wave & 3) << 2;    // B-frag base (warp_n * 4)

  const int wg = blockIdx.x;          // no XCD swizzle (L3-fit)
  const int tm = M >> 8;
  const int m0 = (wg % tm) << 8;
  const int n0 = (wg / tm) << 8;

  // swizzled read offset (bytes) within a 1KB 16x32 subtile
  const int rd_off = ((l16 << 6) + (quad << 4)) ^ ((l16 >> 3) << 5);

  // staging source (inverse-swizzled global address) + LDS dest offset
  const int st_off = wave << 9;       // shorts: subtile (f*2+kb) = qi*8 + wave
  const int src_c  = ((wave & 1) << 5) + (((lane & 3) << 3) ^ ((lane >> 5) << 4));
  const unsigned short* Asrc = A + (size_t)(m0 + ((wave >> 1) << 4) + (lane >> 2)) * K + src_c;
  const unsigned short* Bsrc = B + (size_t)(n0 + ((wave >> 1) << 4) + (lane >> 2)) * K + src_c;

  const int NT = K >> 6;

#define STA(t, qi) GLD16(Asrc + (size_t)(qi) * 64 * K + (t) * 64, \
                         lds + (((t) & 1) << 15) + st_off + ((qi) << 12))
#define STB(t, qi) GLD16(Bsrc + (size_t)(qi) * 64 * K + (t) * 64, \
                         lds + (((t) & 1) << 15) + 16384 + st_off + ((qi) << 12))
#define RDA(dst, P)                                                            \
  _Pragma("unroll")                                                            \
  for (int j = 0; j < 2; ++j)                                                  \
    _Pragma("unroll")                                                          \
    for (int kb = 0; kb < 2; ++kb)                                             \
      dst[j][kb] = *(const bf16x8*)(Ar + ((((wm8 + 2 * (P) + j) << 1) | kb) << 10) + rd_off);
#define MMA(P, AF)                                                             \
  __builtin_amdgcn_s_setprio(1);                                               \
  _Pragma("unroll")                                                            \
  for (int j = 0; j < 2; ++j)                                                  \
    _Pragma("unroll")                                                          \
    for (int nf = 0; nf < 4; ++nf)                                             \
      _Pragma("unroll")                                                        \
      for (int kb = 0; kb < 2; ++kb)                                           \
        acc[2 * (P) + j][nf] = MFMA_BF16(AF[j][kb], b8[nf][kb], acc[2 * (P) + j][nf]); \
  __builtin_amdgcn_s_setprio(0);
#define LGKM4  asm volatile("s_waitcnt lgkmcnt(4)" ::: "memory");              \
               __builtin_amdgcn_sched_barrier(0)
#define LGKM0  asm volatile("s_waitcnt lgkmcnt(0)" ::: "memory");              \
               __builtin_amdgcn_sched_barrier(0)

  f32x4 acc[8][4];
  #pragma unroll
  for (int a = 0; a < 8; ++a)
    #pragma unroll
    for (int b = 0; b < 4; ++b)
      #pragma unroll
      for (int r = 0; r < 4; ++r) acc[a][b][r] = 0.f;

  // ---- prologue: tile 0 full (8 rounds) + tile 1 minus {Aq1,Aq3} (6) ----
  STB(0, 0); STB(0, 1); STB(0, 2); STB(0, 3);
  STA(0, 0); STA(0, 1); STA(0, 2); STA(0, 3);
  if (NT > 1) {
    STB(1, 0); STB(1, 1); STB(1, 2); STB(1, 3); STA(1, 0); STA(1, 2);
    asm volatile("s_waitcnt vmcnt(6)" ::: "memory");
  } else {
    asm volatile("s_waitcnt vmcnt(0)" ::: "memory");
  }
  __builtin_amdgcn_s_barrier();

  for (int u = 0; u < NT; ++u) {
    const char* Ar = (const char*)lds + ((u & 1) << 16);
    const char* Br = Ar + 32768;
    bf16x8 b8[4][2], aA[2][2], aB[2][2];
    // tile-top read group: all B-frags + P0 A-frags (drain under P0's wait)
    #pragma unroll
    for (int nf = 0; nf < 4; ++nf)
      #pragma unroll
      for (int kb = 0; kb < 2; ++kb)
        b8[nf][kb] = *(const bf16x8*)(Br + ((((wn4 + nf) << 1) | kb) << 10) + rd_off);
    RDA(aA, 0);
    __builtin_amdgcn_sched_barrier(0);   // group boundary for lgkm counting

    // ---- P0: issue P1 frags, stage, wait tile-top group, MFMA P0 ----
    RDA(aB, 1);
    if (u + 1 < NT) { STA(u + 1, 1); STA(u + 1, 3); }
    __builtin_amdgcn_s_barrier();
    LGKM4;
    MMA(0, aA);
    __builtin_amdgcn_s_barrier();

    // ---- P1: issue P2 frags, stage, wait P1 frags, MFMA P1 ----
    RDA(aA, 2);
    if (u + 2 < NT) { STB(u + 2, 0); STB(u + 2, 1); }
    __builtin_amdgcn_s_barrier();
    LGKM4;
    MMA(1, aB);
    __builtin_amdgcn_s_barrier();

    // ---- P2: issue P3 frags, stage, wait P2 frags, MFMA P2 ----
    RDA(aB, 3);
    if (u + 2 < NT) { STB(u + 2, 2); STA(u + 2, 0); }
    __builtin_amdgcn_s_barrier();
    LGKM4;
    MMA(2, aA);
    __builtin_amdgcn_s_barrier();

    // ---- P3: stage, wait P3 frags, MFMA P3, boundary vmcnt ----
    if (u + 2 < NT) { STB(u + 2, 3); STA(u + 2, 2); }
    __builtin_amdgcn_s_barrier();
    LGKM0;
    MMA(3, aB);
    if (u + 2 < NT) asm volatile("s_waitcnt vmcnt(6)" ::: "memory");
    else            asm volatile("s_waitcnt vmcnt(0)" ::: "memory");
    __builtin_amdgcn_s_barrier();
  }
#undef RDA
#undef MMA
#undef LGKM4
#undef LGKM0
#undef STA
#undef STB

  // ---- epilogue: bf16 store ----
  #pragma unroll
  for (int mt = 0; mt < 8; ++mt) {
    int row = m0 + ((wave >> 2) << 7) + mt * 16 + (quad << 2);
    #pragma unroll
    for (int nf = 0; nf < 4; ++nf) {
      int col = n0 + ((wave & 3) << 6) + nf * 16 + l16;
      #pragma unroll
      for (int r = 0; r < 4; ++r)
        C[(size_t)(row + r) * N + col] = f2bf(acc[mt][nf][r]);
    }
  }
}

// ---------------------------------------------------------------------------
// 128x256-tile 8-phase pipelined GEMM, fp32 out: C = A[M][K] * B[N][K]^T.
// For GEMM2 (M=4096, N=2048): grid 32x8 = 256 wgs = exactly 1 round. Frozen.
__global__ __launch_bounds__(512, 2) void gemm128x256_bt(
    const unsigned short* __restrict__ A,
    const unsigned short* __restrict__ B,
    float* __restrict__ C, int M, int N, int K)
{
  __shared__ __attribute__((aligned(16))) unsigned short lds[49152]; // 96 KiB

  const int tid  = threadIdx.x;
  const int wave = tid >> 6, lane = tid & 63;
  const int quad = lane >> 4, l16 = lane & 15;
  const int wm4 = (wave >> 2) << 2;   // A-frag base (0 or 4)
  const int wn4 = (wave & 3) << 2;    // B-frag base (0,4,8,12)

  int wg = blockIdx.x;
  if ((gridDim.x & 7) == 0) {
    int qq = (int)gridDim.x >> 3;
    wg = (wg & 7) * qq + (wg >> 3);
  }
  const int tm = M >> 7;
  const int m0 = (wg % tm) << 7;
  const int n0 = (wg / tm) << 8;

  const int rd_off = ((l16 << 6) + (quad << 4)) ^ ((l16 >> 3) << 5);
  const int st_off = wave << 9;       // shorts
  const int src_c  = ((wave & 1) << 5) + (((lane & 3) << 3) ^ ((lane >> 5) << 4));
  const unsigned short* Asrc = A + (size_t)(m0 + ((wave >> 1) << 4) + (lane >> 2)) * K + src_c;
  const unsigned short* Bsrc = B + (size_t)(n0 + ((wave >> 1) << 4) + (lane >> 2)) * K + src_c;

  const int NT = K >> 6;

#define STA(t, qi) GLD16(Asrc + (size_t)(qi) * 64 * K + (t) * 64, \
                         lds + (((t) & 1) * 24576) + st_off + ((qi) << 12))
#define STB(t, qi) GLD16(Bsrc + (size_t)(qi) * 64 * K + (t) * 64, \
                         lds + (((t) & 1) * 24576) + 8192 + st_off + ((qi) << 12))

  f32x4 acc[4][4];
  #pragma unroll
  for (int a = 0; a < 4; ++a)
    #pragma unroll
    for (int b = 0; b < 4; ++b)
      #pragma unroll
      for (int r = 0; r < 4; ++r) acc[a][b][r] = 0.f;

  // ---- prologue: tile 0 full (6 rounds) + tile 1 B (4 rounds) ----
  STB(0, 0); STB(0, 1); STB(0, 2); STB(0, 3);
  STA(0, 0); STA(0, 1);
  if (NT > 1) {
    STB(1, 0); STB(1, 1); STB(1, 2); STB(1, 3);
    asm volatile("s_waitcnt vmcnt(4)" ::: "memory");
  } else {
    asm volatile("s_waitcnt vmcnt(0)" ::: "memory");
  }
  __builtin_amdgcn_s_barrier();

  for (int u = 0; u < NT; ++u) {
    const char* Ar = (const char*)lds + (u & 1) * 49152;
    const char* Br = Ar + 16384;
    bf16x8 b8[4][2], aA[2][2], aB[2][2];
    // tile-top: all 8 B-frags + Pa's 4 A-frags (drain at Pa's lgkmcnt(4))
    #pragma unroll
    for (int nf = 0; nf < 4; ++nf)
      #pragma unroll
      for (int kb = 0; kb < 2; ++kb)
        b8[nf][kb] = *(const bf16x8*)(Br + ((((wn4 + nf) << 1) | kb) << 10) + rd_off);
    #pragma unroll
    for (int j = 0; j < 2; ++j)
      #pragma unroll
      for (int kb = 0; kb < 2; ++kb)
        aA[j][kb] = *(const bf16x8*)(Ar + ((((wm4 + j) << 1) | kb) << 10) + rd_off);
    __builtin_amdgcn_sched_barrier(0);

    // ---- Pa: issue Pb A-frags, stage A(u+1), wait top group, 16 MFMA ----
    #pragma unroll
    for (int j = 0; j < 2; ++j)
      #pragma unroll
      for (int kb = 0; kb < 2; ++kb)
        aB[j][kb] = *(const bf16x8*)(Ar + ((((wm4 + 2 + j) << 1) | kb) << 10) + rd_off);
    if (u + 1 < NT) { STA(u + 1, 0); STA(u + 1, 1); }
    __builtin_amdgcn_s_barrier();
    asm volatile("s_waitcnt lgkmcnt(4)" ::: "memory");
    __builtin_amdgcn_sched_barrier(0);
    __builtin_amdgcn_s_setprio(1);
    #pragma unroll
    for (int j = 0; j < 2; ++j)
      #pragma unroll
      for (int nf = 0; nf < 4; ++nf)
        #pragma unroll
        for (int kb = 0; kb < 2; ++kb)
          acc[j][nf] = MFMA_BF16(aA[j][kb], b8[nf][kb], acc[j][nf]);
    __builtin_amdgcn_s_setprio(0);
    __builtin_amdgcn_s_barrier();

    // ---- Pb: stage B(u+2), wait Pb A-frags, 16 MFMA, boundary vmcnt ----
    if (u + 2 < NT) { STB(u + 2, 0); STB(u + 2, 1); STB(u + 2, 2); STB(u + 2, 3); }
    __builtin_amdgcn_s_barrier();
    asm volatile("s_waitcnt lgkmcnt(0)" ::: "memory");
    __builtin_amdgcn_sched_barrier(0);
    __builtin_amdgcn_s_setprio(1);
    #pragma unroll
    for (int j = 0; j < 2; ++j)
      #pragma unroll
      for (int nf = 0; nf < 4; ++nf)
        #pragma unroll
        for (int kb = 0; kb < 2; ++kb)
          acc[2 + j][nf] = MFMA_BF16(aB[j][kb], b8[nf][kb], acc[2 + j][nf]);
    __builtin_amdgcn_s_setprio(0);
    if (u + 2 < NT) asm volatile("s_waitcnt vmcnt(4)" ::: "memory");
    else            asm volatile("s_waitcnt vmcnt(0)" ::: "memory");
    __builtin_amdgcn_s_barrier();
  }
#undef STA
#undef STB

  // ---- epilogue: fp32 store ----
  #pragma unroll
  for (int mt = 0; mt < 4; ++mt) {
    int row = m0 + ((wave >> 2) << 6) + mt * 16 + (quad << 2);
    #pragma unroll
    for (int nf = 0; nf < 4; ++nf) {
      int col = n0 + ((wave & 3) << 6) + nf * 16 + l16;
      #pragma unroll
      for (int r = 0; r < 4; ++r)
        C[(size_t)(row + r) * N + col] = acc[mt][nf][r];
    }
  }
}

// ---------------------------------------------------------------------------
// ba = H @ W_ba (fp32), beta = sigmoid(b), g = -exp(A_log)*softplus(a+dt_bias)
// R10: grid 1024 (1 row/wave -> 4x TLP) + float4 H loads. Kept.
__global__ __launch_bounds__(256) void ba_kernel(
    const float* __restrict__ H, const float* __restrict__ Wba,
    const float* __restrict__ dtb, const float* __restrict__ Alog,
    float* __restrict__ bbuf, float* __restrict__ gbuf)
{
  int t = threadIdx.x;
  int col = t & 63, wv = t >> 6;
  int m = blockIdx.x * 4 + wv;
  const float* h0 = H + (size_t)m * 2048;
  float acc = 0.f;
  for (int k = 0; k < 2048; k += 4) {
    float4 hv = *(const float4*)(h0 + k);
    acc += hv.x * Wba[(k + 0) * 64 + col];
    acc += hv.y * Wba[(k + 1) * 64 + col];
    acc += hv.z * Wba[(k + 2) * 64 + col];
    acc += hv.w * Wba[(k + 3) * 64 + col];
  }
  int b = m >> 11, s = m & 2047;
  if (col < 32) {
    bbuf[((size_t)(b * 32 + col)) * 2048 + s] = 1.f / (1.f + __expf(-acc));
  } else {
    int hh = col - 32;
    float x  = acc + dtb[hh];
    float sp = (x > 20.f) ? x : log1pf(__expf(x));
    gbuf[((size_t)(b * 32 + hh)) * 2048 + s] = -__expf(Alog[hh]) * sp;
  }
}

// ---------------------------------------------------------------------------
// causal depthwise conv (K=4) + silu + (q,k) l2-norm (q also * DK^-0.5)
// R9: vectorized — 8 cols/thread (bf16x8 16B loads/stores), 16 thr/head,
// 8 heads per 128-thr block, grid (1024, 8). Norm reduce = in-wave 16-lane
// shfl_xor (no LDS, no syncthreads).
__global__ __launch_bounds__(128) void conv_kernel(
    const unsigned short* __restrict__ qkvz, const float* __restrict__ cw,
    unsigned short* __restrict__ qn, unsigned short* __restrict__ kn,
    unsigned short* __restrict__ vb)
{
  int s_base = blockIdx.x * 4;
  int head   = blockIdx.y * 8 + (threadIdx.x >> 4);
  int c8     = (threadIdx.x & 15) * 8;
  int col    = head * 128 + c8;
  int s_loc  = s_base & 2047;

  float vin[7][8];
  #pragma unroll
  for (int t = 0; t < 7; ++t) {
    int sp = s_loc + t - 3;
    if (sp >= 0) {
      bf16x8 v = *(const bf16x8*)(qkvz + (size_t)(s_base + t - 3) * 12288 + col);
      #pragma unroll
      for (int j = 0; j < 8; ++j) vin[t][j] = bf2f((unsigned short)v[j]);
    } else {
      #pragma unroll
      for (int j = 0; j < 8; ++j) vin[t][j] = 0.f;
    }
  }
  float w[8][4];
  #pragma unroll
  for (int j = 0; j < 8; ++j) {
    float4 wv = *(const float4*)(cw + (size_t)(col + j) * 4);
    w[j][0] = wv.x; w[j][1] = wv.y; w[j][2] = wv.z; w[j][3] = wv.w;
  }
  float y[4][8];
  #pragma unroll
  for (int u = 0; u < 4; ++u)
    #pragma unroll
    for (int j = 0; j < 8; ++j) {
      float acc = vin[u][j]*w[j][0] + vin[u+1][j]*w[j][1]
                + vin[u+2][j]*w[j][2] + vin[u+3][j]*w[j][3];
      y[u][j] = acc / (1.f + __expf(-acc));
    }

  if (head < 32) {
    #pragma unroll
    for (int u = 0; u < 4; ++u) {
      float ss = 0.f;
      #pragma unroll
      for (int j = 0; j < 8; ++j) ss += y[u][j] * y[u][j];
      ss += __shfl_xor(ss, 1);
      ss += __shfl_xor(ss, 2);
      ss += __shfl_xor(ss, 4);
      ss += __shfl_xor(ss, 8);
      float r = rsqrtf(ss + 1e-6f);
      bf16x8 out;
      if (head < 16) {
        float rq = r * 0.08838834764831845f;
        #pragma unroll
        for (int j = 0; j < 8; ++j) out[j] = (short)f2bf(y[u][j] * rq);
        *(bf16x8*)(qn + ((size_t)(s_base + u) * 16 + head) * 128 + c8) = out;
      } else {
        #pragma unroll
        for (int j = 0; j < 8; ++j) out[j] = (short)f2bf(y[u][j] * r);
        *(bf16x8*)(kn + ((size_t)(s_base + u) * 16 + (head - 16)) * 128 + c8) = out;
      }
    }
  } else {
    #pragma unroll
    for (int u = 0; u < 4; ++u) {
      bf16x8 out;
      #pragma unroll
      for (int j = 0; j < 8; ++j) out[j] = (short)f2bf(y[u][j]);
      *(bf16x8*)(vb + ((size_t)(s_base + u) * 32 + (head - 32)) * 128 + c8) = out;
    }
  }
}

// ---------------------------------------------------------------------------
// per-chunk: A=(beta k)k^T * decay (strict lower), attn=q k^T * decay,
// register-column forward substitution (no barriers), outputs packed for scan.
__global__ __launch_bounds__(256) void chunk_kernel(
    const unsigned short* __restrict__ qnb, const unsigned short* __restrict__ knb,
    const unsigned short* __restrict__ vbb,
    const float* __restrict__ gbuf, const float* __restrict__ bbuf,
    unsigned short* __restrict__ attnb, unsigned short* __restrict__ vadjb,
    unsigned short* __restrict__ kcdn, unsigned short* __restrict__ qgb,
    unsigned short* __restrict__ kdT, float* __restrict__ egl)
{
  int cid = blockIdx.x;
  int n = cid & 31, h = (cid >> 5) & 31, b = cid >> 10;
  int h2 = h >> 1, s0 = n * 64;
  int gs0 = b * 2048 + s0;
  int tid = threadIdx.x, wave = tid >> 6, lane = tid & 63, quad = lane >> 4, l16 = lane & 15;

  __shared__ __attribute__((aligned(16))) unsigned short kS[64 * 136]; // bf16 k tile
  __shared__ __attribute__((aligned(16))) float As[64 * 68];           // fp32 A (strict lower)
  __shared__ float gcS[64], betaS[64];
  __shared__ float rsV[64], rsK[64], egq[64], egliS[64];

  if (tid < 64) {
    gcS[tid]   = gbuf[((size_t)(b * 32 + h)) * 2048 + s0 + tid];
    betaS[tid] = bbuf[((size_t)(b * 32 + h)) * 2048 + s0 + tid];
  }
  {                               // stage k tile -> LDS (bf16 copy)
    int i = tid >> 2, seg = tid & 3;
    const bf16x8* kp = (const bf16x8*)(knb + ((size_t)(gs0 + i) * 16 + h2) * 128 + seg * 32);
    bf16x8* kd_ = (bf16x8*)(kS + i * 136 + seg * 32);
    #pragma unroll
    for (int u = 0; u < 4; ++u) kd_[u] = kp[u];
  }
  __syncthreads();                // B1: gcS/betaS/kS staged
  if (tid == 0) {                 // inclusive cumsum of g
    float run = 0.f;
    for (int i = 0; i < 64; ++i) { run += gcS[i]; gcS[i] = run; }
  }
  __syncthreads();                // B2: cumsum done

  if (tid < 64) {                 // per-row scales (concurrent with phase 1)
    float gi = gcS[tid];
    rsV[tid]   = betaS[tid];
    rsK[tid]   = betaS[tid] * __expf(gi);
    egq[tid]   = __expf(gi);
    egliS[tid] = __expf(gcS[63] - gi);
    if (tid == 0) egl[cid] = __expf(gcS[63]);
  }

  // phase 1: A and attn via MFMA (wave w owns i-tile w)
  {
    int arow = wave * 16 + l16;
    float bscale = betaS[arow];
    const unsigned short* qpg = qnb + ((size_t)(gs0 + arow) * 16 + h2) * 128;
    bf16x8 kbf[4], qf[4];
    #pragma unroll
    for (int ks = 0; ks < 4; ++ks) {
      bf16x8 kfr = *(const bf16x8*)(kS + arow * 136 + ks * 32 + quad * 8);
      bf16x8 t;
      #pragma unroll
      for (int e = 0; e < 8; ++e)
        t[e] = (short)f2bf(bf2f((unsigned short)kfr[e]) * bscale);
      kbf[ks] = t;
      qf[ks] = *(const bf16x8*)(qpg + ks * 32 + quad * 8);
    }
    #pragma unroll
    for (int jt = 0; jt < 4; ++jt) {
      f32x4 accA, accQ;
      #pragma unroll
      for (int r = 0; r < 4; ++r) { accA[r] = 0.f; accQ[r] = 0.f; }
      #pragma unroll
      for (int ks = 0; ks < 4; ++ks) {
        bf16x8 bfr = *(const bf16x8*)(kS + (jt * 16 + l16) * 136 + ks * 32 + quad * 8);
        accA = MFMA_BF16(kbf[ks], bfr, accA);
        accQ = MFMA_BF16(qf[ks],  bfr, accQ);
      }
      #pragma unroll
      for (int r = 0; r < 4; ++r) {
        int i = wave * 16 + quad * 4 + r;
        int j = jt * 16 + l16;
        float e = __expf(gcS[i] - gcS[j]);
        As[i * 68 + j] = (j < i) ? (accA[r] * e) : 0.f;
        attnb[(size_t)cid * 4096 + i * 64 + j] = (j <= i) ? f2bf(accQ[r] * e) : (unsigned short)0;
      }
    }
  }
  __syncthreads();                // B3: As + rs arrays ready

  // phase 2+3: per-thread register column + blocked forward substitution.
  // thread c<128 owns v-column c; thread c>=128 owns k-column c-128.
  {
    int c = tid;
    float x[64];
    if (c < 128) {
      const unsigned short* vp = vbb + ((size_t)gs0 * 32 + h) * 128 + c;
      #pragma unroll
      for (int i = 0; i < 64; ++i)
        x[i] = bf2f(vp[(size_t)i * 4096]) * rsV[i];
    } else {
      int ck = c - 128;
      #pragma unroll
      for (int i = 0; i < 64; ++i)
        x[i] = bf2f(kS[i * 136 + ck]) * rsK[i];
    }
    // blocked forward substitution: As strict-lower (zeros on/above diag make
    // full 16-wide row updates safe).
    #pragma unroll
    for (int bi = 0; bi < 4; ++bi) {
      const int base = bi * 16;
      // serial in-block rows
      #pragma unroll
      for (int ii = 1; ii < 16; ++ii) {
        const int r = base + ii;
        const f32x4* ar = (const f32x4*)(As + r * 68 + base);
        float s = 0.f;
        #pragma unroll
        for (int g = 0; g < 4; ++g) {
          f32x4 a4 = ar[g];
          s += a4[0] * x[base + g*4] + a4[1] * x[base + g*4 + 1]
             + a4[2] * x[base + g*4 + 2] + a4[3] * x[base + g*4 + 3];
        }
        x[r] -= s;
      }
      // batch update of rows below this block
      #pragma unroll
      for (int r = base + 16; r < 64; ++r) {
        const f32x4* ar = (const f32x4*)(As + r * 68 + base);
        float s = 0.f;
        #pragma unroll
        for (int g = 0; g < 4; ++g) {
          f32x4 a4 = ar[g];
          s += a4[0] * x[base + g*4] + a4[1] * x[base + g*4 + 1]
             + a4[2] * x[base + g*4 + 2] + a4[3] * x[base + g*4 + 3];
        }
        x[r] -= s;
      }
    }
    // column store: vadj (c<128) / negated kcd (c>=128), coalesced 2B stores
    if (c < 128) {
      unsigned short* vo = vadjb + (size_t)cid * 8192 + c;
      #pragma unroll
      for (int i = 0; i < 64; ++i) vo[i * 128] = f2bf(x[i]);
    } else {
      unsigned short* ko = kcdn + (size_t)cid * 8192 + (c - 128);
      #pragma unroll
      for (int i = 0; i < 64; ++i) ko[i * 128] = f2bf(-x[i]);
    }
  }

  // phase 4: pack qg (q * e^gc) and kdT (k * e^(g_last - gc), transposed)
  {
    int i = tid >> 2, seg = tid & 3;
    float egli = egliS[i];
    float eqi  = egq[i];
    size_t base128 = (size_t)cid * 8192 + i * 128 + seg * 32;
    const unsigned short* qp = qnb + ((size_t)(gs0 + i) * 16 + h2) * 128 + seg * 32;
    #pragma unroll
    for (int u = 0; u < 32; u += 4) {
      *(unsigned long long*)(qgb + base128 + u) =
          pack4bf(bf2f(qp[u]) * eqi, bf2f(qp[u+1]) * eqi, bf2f(qp[u+2]) * eqi, bf2f(qp[u+3]) * eqi);
    }
    const unsigned short* kp = kS + i * 136 + seg * 32;
    unsigned short* kdo = kdT + (size_t)cid * 8192;
    #pragma unroll
    for (int u = 0; u < 32; ++u) {
      int d = seg * 32 + u;
      kdo[(size_t)d * 64 + i] = f2bf(bf2f(kp[u]) * egli);
    }
  }
}

// ---------------------------------------------------------------------------
// sequential scan over 32 chunks. grid (64 bh, 4 dv-slices of 32).
// R8 PROVEN form: depth-2 register prefetch (two named sets, unconditional
// loads in the 2-step rotation). Reverted from depth-3 (R10 regression).
struct ScanPref {
  bf16x8 kf[4], qf[4], af2[2], kdf[2][2];
  float  vinit[2][4];
  float  a;
};

__device__ __forceinline__ void scan_load(
    ScanPref& p, size_t cid,
    const unsigned short* __restrict__ qgb, const unsigned short* __restrict__ kcdn,
    const unsigned short* __restrict__ attnb, const unsigned short* __restrict__ kdT,
    const unsigned short* __restrict__ vadjb, const float* __restrict__ egl,
    int w, int quad, int l16, int dv0)
{
  const unsigned short* qgc = qgb  + cid * 8192;
  const unsigned short* kcc = kcdn + cid * 8192;
  const unsigned short* atc = attnb + cid * 4096;
  const unsigned short* kdc = kdT  + cid * 8192;
  const unsigned short* vac = vadjb + cid * 8192;
  p.a = egl[cid];
  #pragma unroll
  for (int ks = 0; ks < 4; ++ks) {
    p.kf[ks] = *(const bf16x8*)(kcc + (size_t)(w * 16 + l16) * 128 + ks * 32 + quad * 8);
    p.qf[ks] = *(const bf16x8*)(qgc + (size_t)(w * 16 + l16) * 128 + ks * 32 + quad * 8);
  }
  #pragma unroll
  for (int k2 = 0; k2 < 2; ++k2)
    p.af2[k2] = *(const bf16x8*)(atc + (size_t)(w * 16 + l16) * 64 + k2 * 32 + quad * 8);
  #pragma unroll
  for (int mi = 0; mi < 2; ++mi)
    #pragma unroll
    for (int k2 = 0; k2 < 2; ++k2)
      p.kdf[mi][k2] = *(const bf16x8*)(kdc + (size_t)((w * 2 + mi) * 16 + l16) * 64 + k2 * 32 + quad * 8);
  #pragma unroll
  for (int ni = 0; ni < 2; ++ni)
    #pragma unroll
    for (int r = 0; r < 4; ++r)
      p.vinit[ni][r] = bf2f(vac[(size_t)(w * 16 + quad * 4 + r) * 128 + dv0 + ni * 16 + l16]);
}

__device__ __forceinline__ void scan_step(
    const ScanPref& p, f32x4 st[2][2],
    unsigned short* stT, unsigned short* vnT,
    unsigned short* __restrict__ obuf, int bh, int n,
    int w, int quad, int l16, int dv0)
{
  bf16x8 sf[2][4];
  #pragma unroll
  for (int ni = 0; ni < 2; ++ni)
    #pragma unroll
    for (int ks = 0; ks < 4; ++ks)
      sf[ni][ks] = *(const bf16x8*)(stT + (ni * 16 + l16) * 136 + ks * 32 + quad * 8);

  // v_new = v_adj - kcd @ state  (kcd stored negated)
  f32x4 vacc[2];
  #pragma unroll
  for (int ni = 0; ni < 2; ++ni)
    #pragma unroll
    for (int r = 0; r < 4; ++r) vacc[ni][r] = p.vinit[ni][r];
  #pragma unroll
  for (int ni = 0; ni < 2; ++ni)
    #pragma unroll
    for (int ks = 0; ks < 4; ++ks)
      vacc[ni] = MFMA_BF16(p.kf[ks], sf[ni][ks], vacc[ni]);

  // o (part1) = (q e^gc) @ state
  f32x4 oacc[2];
  #pragma unroll
  for (int ni = 0; ni < 2; ++ni)
    #pragma unroll
    for (int r = 0; r < 4; ++r) oacc[ni][r] = 0.f;
  #pragma unroll
  for (int ni = 0; ni < 2; ++ni)
    #pragma unroll
    for (int ks = 0; ks < 4; ++ks)
      oacc[ni] = MFMA_BF16(p.qf[ks], sf[ni][ks], oacc[ni]);

  // publish v_new^T
  #pragma unroll
  for (int ni = 0; ni < 2; ++ni)
    #pragma unroll
    for (int r = 0; r < 4; ++r)
      vnT[(ni * 16 + l16) * 72 + w * 16 + quad * 4 + r] = f2bf(vacc[ni][r]);
  __syncthreads();

  // o (part2) += attn @ v_new ; store o (bf16)
  bf16x8 vf[2][2];
  #pragma unroll
  for (int ni = 0; ni < 2; ++ni)
    #pragma unroll
    for (int k2 = 0; k2 < 2; ++k2)
      vf[ni][k2] = *(const bf16x8*)(vnT + (ni * 16 + l16) * 72 + k2 * 32 + quad * 8);
  #pragma unroll
  for (int ni = 0; ni < 2; ++ni)
    #pragma unroll
    for (int k2 = 0; k2 < 2; ++k2)
      oacc[ni] = MFMA_BF16(p.af2[k2], vf[ni][k2], oacc[ni]);
  unsigned short* op = obuf + ((size_t)bh * 2048 + n * 64) * 128;
  #pragma unroll
  for (int ni = 0; ni < 2; ++ni)
    #pragma unroll
    for (int r = 0; r < 4; ++r)
      op[(size_t)(w * 16 + quad * 4 + r) * 128 + dv0 + ni * 16 + l16] = f2bf(oacc[ni][r]);

  // state = a*state + kdT @ v_new  (fp32 master in regs)
  #pragma unroll
  for (int mi = 0; mi < 2; ++mi) {
    #pragma unroll
    for (int ni = 0; ni < 2; ++ni) {
      f32x4 acc_;
      #pragma unroll
      for (int r = 0; r < 4; ++r) acc_[r] = p.a * st[mi][ni][r];
      #pragma unroll
      for (int k2 = 0; k2 < 2; ++k2)
        acc_ = MFMA_BF16(p.kdf[mi][k2], vf[ni][k2], acc_);
      st[mi][ni] = acc_;
    }
  }
  // publish state^T bf16 for next chunk
  #pragma unroll
  for (int mi = 0; mi < 2; ++mi)
    #pragma unroll
    for (int ni = 0; ni < 2; ++ni)
      #pragma unroll
      for (int r = 0; r < 4; ++r)
        stT[(ni * 16 + l16) * 136 + (w * 2 + mi) * 16 + quad * 4 + r] = f2bf(st[mi][ni][r]);
  __syncthreads();
}

__global__ __launch_bounds__(256, 1) void scan_kernel(
    const unsigned short* __restrict__ qgb, const unsigned short* __restrict__ kcdn,
    const unsigned short* __restrict__ attnb, const unsigned short* __restrict__ kdT,
    const unsigned short* __restrict__ vadjb, const float* __restrict__ egl,
    unsigned short* __restrict__ obuf)
{
  int bh = blockIdx.x, dv0 = blockIdx.y * 32;
  int tid = threadIdx.x, w = tid >> 6, quad = (tid & 63) >> 4, l16 = tid & 15;
  __shared__ __attribute__((aligned(16))) unsigned short stT[32 * 136];
  __shared__ __attribute__((aligned(16))) unsigned short vnT[32 * 72];

  for (int idx = tid; idx < 32 * 136; idx += 256) stT[idx] = 0;
  f32x4 st[2][2];
  #pragma unroll
  for (int a = 0; a < 2; ++a)
    #pragma unroll
    for (int bq = 0; bq < 2; ++bq)
      #pragma unroll
      for (int r = 0; r < 4; ++r) st[a][bq][r] = 0.f;

  ScanPref pA, pB;
  scan_load(pA, (size_t)bh * 32, qgb, kcdn, attnb, kdT, vadjb, egl, w, quad, l16, dv0);
  __syncthreads();

  for (int n = 0; n < 32; n += 2) {
    scan_load(pB, (size_t)bh * 32 + n + 1, qgb, kcdn, attnb, kdT, vadjb, egl, w, quad, l16, dv0);
    scan_step(pA, st, stT, vnT, obuf, bh, n, w, quad, l16, dv0);
    if (n + 2 < 32)
      scan_load(pA, (size_t)bh * 32 + n + 2, qgb, kcdn, attnb, kdT, vadjb, egl, w, quad, l16, dv0);
    scan_step(pB, st, stT, vnT, obuf, bh, n + 1, w, quad, l16, dv0);
  }
}

// ---------------------------------------------------------------------------
// gated RMSNorm: rmsnorm(o)*w*silu(z) -> gated bf16.
// R9: vectorized — 8 elems/thread (bf16x8), 16 thr/row, 16 rows per
// 256-thr block, grid 8192. Reduce = in-wave 16-lane shfl_xor.
__global__ __launch_bounds__(256) void gate_kernel(
    const unsigned short* __restrict__ obuf, const unsigned short* __restrict__ qkvz,
    const float* __restrict__ nw, unsigned short* __restrict__ gated)
{
  int id = blockIdx.x * 16 + (threadIdx.x >> 4);  // (b*2048+s)*32 + h
  int h = id & 31, bs = id >> 5;
  int b = bs >> 11, s = bs & 2047;
  int c8 = (threadIdx.x & 15) * 8;
  const unsigned short* op = obuf + (((size_t)(b * 32 + h)) * 2048 + s) * 128 + c8;
  const unsigned short* zp = qkvz + (size_t)bs * 12288 + 8192 + h * 128 + c8;

  bf16x8 xv = *(const bf16x8*)op;
  float x[8];
  float ss = 0.f;
  #pragma unroll
  for (int j = 0; j < 8; ++j) { x[j] = bf2f((unsigned short)xv[j]); ss += x[j] * x[j]; }
  ss += __shfl_xor(ss, 1);
  ss += __shfl_xor(ss, 2);
  ss += __shfl_xor(ss, 4);
  ss += __shfl_xor(ss, 8);
  float r = rsqrtf(ss * (1.f / 128.f) + 1e-6f);

  bf16x8 zv = *(const bf16x8*)zp;
  float4 nw0 = *(const float4*)(nw + c8);
  float4 nw1 = *(const float4*)(nw + c8 + 4);
  float nwv[8] = {nw0.x, nw0.y, nw0.z, nw0.w, nw1.x, nw1.y, nw1.z, nw1.w};
  bf16x8 out;
  #pragma unroll
  for (int j = 0; j < 8; ++j) {
    float z = bf2f((unsigned short)zv[j]);
    float g = z / (1.f + __expf(-z));
    out[j] = (short)f2bf(x[j] * r * nwv[j] * g);
  }
  *(bf16x8*)(gated + (size_t)bs * 4096 + h * 128 + c8) = out;
}

// ---------------------------------------------------------------------------
extern "C" void kernel_launch(void* const* d_in, const int* in_sizes, int n_in,
                              void* d_out, int out_size, void* d_ws, size_t ws_size,
                              hipStream_t stream)
{
  const float* H     = (const float*)d_in[0];
  const float* Wqkvz = (const float*)d_in[1];
  const float* Wba   = (const float*)d_in[2];
  const float* cw    = (const float*)d_in[3];
  const float* dtb   = (const float*)d_in[4];
  const float* Alog  = (const float*)d_in[5];
  const float* nw    = (const float*)d_in[6];
  const float* Wout  = (const float*)d_in[7];
  float* out = (float*)d_out;

  // ---- workspace arena (370,155,520 B) with aliasing ----
  const size_t U1 = 0;                      //  67,108,864: Hbf+WqT -> qn+kn+vb
  const size_t U2 = U1 + 67108864;          // 100,663,296: qkvz bf16 (z until gate)
  const size_t U3 = U2 + 100663296;         //  16,777,216: WoT
  const size_t U4 = U3 + 16777216;          //   1,048,576: bbuf+gbuf
  const size_t U5 = U4 + 1048576;           // 151,003,136: chunk outputs -> gated
  const size_t U6 = U5 + 151003136;         //  33,554,432: obuf bf16
  const size_t NEED = U6 + 33554432;        // 370,155,520
  if (ws_size < NEED) return;               // graceful fail (diagnostic)

  char* base = (char*)d_ws;
  unsigned short* Hbf   = (unsigned short*)(base + U1);
  unsigned short* WqT   = (unsigned short*)(base + U1 + 16777216);
  unsigned short* qnb   = (unsigned short*)(base + U1);              // after GEMM1
  unsigned short* knb   = (unsigned short*)(base + U1 + 16777216);   // after GEMM1
  unsigned short* vbb   = (unsigned short*)(base + U1 + 33554432);   // after GEMM1
  unsigned short* qkvzb = (unsigned short*)(base + U2);
  unsigned short* WoT   = (unsigned short*)(base + U3);
  float*          bbuf  = (float*)(base + U4);
  float*          gbuf  = (float*)(base + U4 + 524288);
  unsigned short* attnb = (unsigned short*)(base + U5);
  unsigned short* vadjb = (unsigned short*)(base + U5 + 16777216);
  unsigned short* kcdn  = (unsigned short*)(base + U5 + 50331648);
  unsigned short* qgb   = (unsigned short*)(base + U5 + 83886080);
  unsigned short* kdTb  = (unsigned short*)(base + U5 + 117440512);
  float*          egl   = (float*)(base + U5 + 150994944);
  unsigned short* gated = (unsigned short*)(base + U5);              // after scan
  unsigned short* obuf  = (unsigned short*)(base + U6);

  cast_bf16_kernel<<<8192, 256, 0, stream>>>(H, Hbf, 4096 * 2048);
  transpose_cast_kernel<<<dim3(12288 / 32, 2048 / 32), 256, 0, stream>>>(Wqkvz, WqT, 2048, 12288);
  transpose_cast_kernel<<<dim3(2048 / 32, 4096 / 32), 256, 0, stream>>>(Wout, WoT, 4096, 2048);
  // GEMM1: 4096x12288x2048 -> 16x48 = 768 workgroups of 512 thr (256^2 tiles)
  gemm256_bt<<<768, 512, 0, stream>>>(Hbf, WqT, qkvzb, 4096, 12288, 2048);
  ba_kernel<<<1024, 256, 0, stream>>>(H, Wba, dtb, Alog, bbuf, gbuf);
  conv_kernel<<<dim3(1024, 8), 128, 0, stream>>>(qkvzb, cw, qnb, knb, vbb);
  chunk_kernel<<<2048, 256, 0, stream>>>(qnb, knb, vbb, gbuf, bbuf, attnb, vadjb, kcdn, qgb, kdTb, egl);
  scan_kernel<<<dim3(64, 4), 256, 0, stream>>>(qgb, kcdn, attnb, kdTb, vadjb, egl, obuf);
  gate_kernel<<<8192, 256, 0, stream>>>(obuf, qkvzb, nw, gated);
  // GEMM2: 4096x2048x4096 -> 32x8 = 256 workgroups of 512 thr (128x256 tiles)
  gemm128x256_bt<<<256, 512, 0, stream>>>(gated, WoT, out, 4096, 2048, 4096);
}